// Round 14
// baseline (51901.306 us; speedup 1.0000x reference)
//
#include <hip/hip_runtime.h>
#include <hip/hip_bf16.h>
#include <stdint.h>

// ---------------------------------------------------------------------------
// Pointer-network decoder: persistent pair-synced kernel, fence-free.
// Round-13 structure VERBATIM (51.8 ms, replay-proven bit-exact) + ONE change:
// the 128KB LDS tile now holds ctxT[q*128 .. q*128+128)[own l-half] (was
// rows [0,128) for both blocks). Block q's hs slots read exactly rows
// [q*128, q*128+128) -> hs own-half is now LDS-served for BOTH blocks
// (was: block 1 got zero coverage). att volume unchanged (q=0 same as R13,
// q=1 mirrored). Pure source redirection: same bytes, same accumulation
// order, same syncs -> bit-identical pointer trajectory.
// Fallback: round-3 multi-kernel path (passed, 78 ms).
// ---------------------------------------------------------------------------

#define PARTITIONABLE 1

#define B_ 128
#define L_ 512
#define E_ 128
#define H_ 256
#define G4_ 1024
#define CNT_STRIDE 32   // words per pair: one 128B line, no false sharing

#define DVLOAD(p)     __hip_atomic_load((p), __ATOMIC_RELAXED, __HIP_MEMORY_SCOPE_AGENT)
#define DVSTORE(p, v) __hip_atomic_store((p), (v), __ATOMIC_RELAXED, __HIP_MEMORY_SCOPE_AGENT)

// ---------------- Threefry-2x32 (exact JAX reproduction) -------------------
__device__ __forceinline__ void tf2x32(uint32_t k0, uint32_t k1,
                                       uint32_t x0, uint32_t x1,
                                       uint32_t &o0, uint32_t &o1) {
  uint32_t ks2 = k0 ^ k1 ^ 0x1BD11BDAu;
#define TFR(a, b, r) { a += b; b = (b << (r)) | (b >> (32 - (r))); b ^= a; }
  x0 += k0; x1 += k1;
  TFR(x0, x1, 13) TFR(x0, x1, 15) TFR(x0, x1, 26) TFR(x0, x1, 6)
  x0 += k1; x1 += ks2 + 1u;
  TFR(x0, x1, 17) TFR(x0, x1, 29) TFR(x0, x1, 16) TFR(x0, x1, 24)
  x0 += ks2; x1 += k0 + 2u;
  TFR(x0, x1, 13) TFR(x0, x1, 15) TFR(x0, x1, 26) TFR(x0, x1, 6)
  x0 += k0; x1 += k1 + 3u;
  TFR(x0, x1, 17) TFR(x0, x1, 29) TFR(x0, x1, 16) TFR(x0, x1, 24)
  x0 += k1; x1 += ks2 + 4u;
  TFR(x0, x1, 13) TFR(x0, x1, 15) TFR(x0, x1, 26) TFR(x0, x1, 6)
  x0 += ks2; x1 += k0 + 5u;
#undef TFR
  o0 = x0; o1 = x1;
}

__device__ __forceinline__ void step_key(int t, uint32_t &k0, uint32_t &k1) {
#if PARTITIONABLE
  tf2x32(0u, 42u, 0u, (uint32_t)t, k0, k1);
#else
  uint32_t d0, d1;
  uint32_t i = 2u * (uint32_t)t;
  if (t < 256) {
    tf2x32(0u, 42u, i,      512u + i, k0, d1);
    tf2x32(0u, 42u, i + 1u, 513u + i, k1, d1);
  } else {
    tf2x32(0u, 42u, i - 512u, i,      d0, k0);
    tf2x32(0u, 42u, i - 511u, i + 1u, d0, k1);
  }
#endif
}

__device__ __forceinline__ float gumbel_for(uint32_t k0, uint32_t k1, uint32_t j) {
  uint32_t bits, o0, o1;
#if PARTITIONABLE
  tf2x32(k0, k1, 0u, j, o0, o1);
  bits = o0 ^ o1;
#else
  if (j < 32768u) { tf2x32(k0, k1, j, j + 32768u, o0, o1); bits = o0; }
  else            { tf2x32(k0, k1, j - 32768u, j, o0, o1); bits = o1; }
#endif
  float f = __uint_as_float((bits >> 9) | 0x3f800000u) - 1.0f;
  float u = (f > 0.0f) ? f : 1.1754943508222875e-38f;
  return -logf(-logf(u));
}

__device__ __forceinline__ float sigmoidf_(float x) {
  return 1.0f / (1.0f + expf(-x));
}

// ---------------------------------------------------------------------------
// ctx precompute + pair-sync-counter init (replay-safe: runs every launch)
// ---------------------------------------------------------------------------
__global__ __launch_bounds__(256, 2) void ctx_precompute(
    const float* __restrict__ context, const float* __restrict__ Wctx,
    const float* __restrict__ bctx, float* __restrict__ ctxT,
    unsigned* __restrict__ cnt) {
  __shared__ float lctx[64][256];
  if (blockIdx.x == 0) {
    for (int i = threadIdx.x; i < B_ * CNT_STRIDE; i += 256) cnt[i] = 0u;
  }
  int b = blockIdx.x >> 3;
  int l0 = (blockIdx.x & 7) << 6;
  const float* src = context + ((size_t)b * L_ + l0) * H_;
  for (int i = threadIdx.x; i < 64 * 256; i += 256)
    lctx[i >> 8][i & 255] = src[i];
  __syncthreads();
  int k = threadIdx.x;
  float bk = bctx[k];
  for (int g = 0; g < 8; ++g) {
    float acc[8] = {0, 0, 0, 0, 0, 0, 0, 0};
    for (int j = 0; j < H_; ++j) {
      float w = Wctx[(size_t)j * H_ + k];
#pragma unroll
      for (int i = 0; i < 8; ++i) acc[i] = fmaf(lctx[g * 8 + i][j], w, acc[i]);
    }
    float* dst = ctxT + ((size_t)b * H_ + k) * L_ + l0 + g * 8;
#pragma unroll
    for (int i = 0; i < 8; ++i) dst[i] = acc[i] + bk;
  }
}

// ---------------------------------------------------------------------------
// fence-free pair sync (protocol proven bit-exact in rounds 5/6/9/13)
// ---------------------------------------------------------------------------
__device__ __forceinline__ void pair_sync(unsigned* c, unsigned target) {
  __syncthreads();   // drains vmcnt before barrier -> stores visible
  if (threadIdx.x == 0) {
    __hip_atomic_fetch_add(c, 1u, __ATOMIC_RELAXED, __HIP_MEMORY_SCOPE_AGENT);
    while (__hip_atomic_load(c, __ATOMIC_RELAXED, __HIP_MEMORY_SCOPE_AGENT) < target)
      __builtin_amdgcn_s_sleep(1);
  }
  __syncthreads();
}

// ---------------------------------------------------------------------------
// Persistent pair-synced scan: pair (b, b+128), q = blockIdx>>7.
// Dynamic LDS: sctx[128][256] = ctxT[q*128 .. q*128+128)[own l-half].
// ---------------------------------------------------------------------------
__global__ __launch_bounds__(512, 1) void coop_scan(
    const float* __restrict__ embedded, const float* __restrict__ dec_in,
    const float* __restrict__ h0, const float* __restrict__ c0,
    const float* __restrict__ Wih, const float* __restrict__ bih,
    const float* __restrict__ Whh, const float* __restrict__ bhh,
    const float* __restrict__ Wout, const float* __restrict__ bout,
    const float* __restrict__ Winp, const float* __restrict__ binp,
    const float* __restrict__ Vv, const float* __restrict__ ctxT,
    float* __restrict__ gates_ws, float* __restrict__ att_ws,
    float* __restrict__ hs_ws, unsigned* __restrict__ cnt,
    float* __restrict__ out) {
  extern __shared__ float sctx[];   // [128][256]: rows q*128.., own l-half
  __shared__ float sh[H_], sc[H_], sht[H_], sx[E_], sinp[H_], shs[H_];
  __shared__ float salpha[L_], smask[L_];
  __shared__ float sV[H_];
  __shared__ float redp[8];
  __shared__ int redpi[8];
  __shared__ float red_res;
  __shared__ int red_resi;

  const int tid = threadIdx.x;
  const int b = blockIdx.x & 127;
  const int q = blockIdx.x >> 7;
  const int lane = tid & 63, wid = tid >> 6;

  if (tid < H_) {
    sh[tid] = h0[b * H_ + tid];
    sc[tid] = c0[b * H_ + tid];
    sV[tid] = Vv[tid];
  }
  if (tid < E_) sx[tid] = dec_in[b * E_ + tid];
  smask[tid] = 1.0f;

  const float* ctb = ctxT + (size_t)b * H_ * L_;
  // preload LDS ctx tile: rows k in [q*128, q*128+128), l in [q*256, +256)
  for (int i = tid; i < 128 * 256; i += 512)
    sctx[i] = ctb[(size_t)((q << 7) + (i >> 8)) * L_ + (q << 8) + (i & 255)];
  __syncthreads();

  float* outA = out + (size_t)b * L_ * L_;
  float* outP = out + (size_t)B_ * L_ * L_ + (size_t)b * L_;
  float* outH = out + (size_t)B_ * L_ * L_ + (size_t)B_ * L_ + (size_t)b * H_;
  float* outC = outH + (size_t)B_ * H_;
  unsigned* c0p = cnt + b * CNT_STRIDE;   // one 128B line per pair

  const int jP1 = (q << 9) + tid;          // this thread's gate column
  const float bihj = bih[jP1], bhhj = bhh[jP1];
  const float binp_r = (tid < H_) ? binp[tid] : 0.0f;
  const float bout_r = (tid < H_) ? bout[tid] : 0.0f;

  for (int t = 0; t < L_; ++t) {
    // ---- P1: gates[b][j] (verbatim round-6)
    {
      int j = jP1;
      float a0 = 0, a1 = 0, a2 = 0, a3 = 0;
#pragma unroll 4
      for (int k = 0; k < E_; k += 4) {
        const float* w = Wih + (size_t)k * G4_ + j;
        a0 = fmaf(sx[k],     w[0],       a0);
        a1 = fmaf(sx[k + 1], w[G4_],     a1);
        a2 = fmaf(sx[k + 2], w[2 * G4_], a2);
        a3 = fmaf(sx[k + 3], w[3 * G4_], a3);
      }
      float g0 = ((a0 + a1) + (a2 + a3)) + bihj;
      a0 = a1 = a2 = a3 = 0.f;
#pragma unroll 4
      for (int k = 0; k < H_; k += 4) {
        const float* w = Whh + (size_t)k * G4_ + j;
        a0 = fmaf(sh[k],     w[0],       a0);
        a1 = fmaf(sh[k + 1], w[G4_],     a1);
        a2 = fmaf(sh[k + 2], w[2 * G4_], a2);
        a3 = fmaf(sh[k + 3], w[3 * G4_], a3);
      }
      DVSTORE(gates_ws + (size_t)b * G4_ + j, (g0 + ((a0 + a1) + (a2 + a3))) + bhhj);
    }
    pair_sync(c0p + 0, 2u * (unsigned)(t + 1));

    // ---- P2: LSTM pointwise + inp GEMV (redundant) + att own l-half
    if (tid < H_) {
      float ig = DVLOAD(gates_ws + (size_t)b * G4_ + tid);
      float fg = DVLOAD(gates_ws + (size_t)b * G4_ + H_ + tid);
      float gg = DVLOAD(gates_ws + (size_t)b * G4_ + 2 * H_ + tid);
      float og = DVLOAD(gates_ws + (size_t)b * G4_ + 3 * H_ + tid);
      float ct = sigmoidf_(fg) * sc[tid] + sigmoidf_(ig) * tanhf(gg);
      float htv = sigmoidf_(og) * tanhf(ct);
      sc[tid] = ct;
      sht[tid] = htv;
    }
    __syncthreads();
    if (tid < H_) {
      float a0 = 0, a1 = 0, a2 = 0, a3 = 0;
#pragma unroll 4
      for (int jv = 0; jv < H_; jv += 4) {
        a0 = fmaf(sht[jv],     Winp[(size_t)jv * H_ + tid],       a0);
        a1 = fmaf(sht[jv + 1], Winp[(size_t)(jv + 1) * H_ + tid], a1);
        a2 = fmaf(sht[jv + 2], Winp[(size_t)(jv + 2) * H_ + tid], a2);
        a3 = fmaf(sht[jv + 3], Winp[(size_t)(jv + 3) * H_ + tid], a3);
      }
      sinp[tid] = ((a0 + a1) + (a2 + a3)) + binp_r;
    }
    __syncthreads();
    if (tid < H_) {
      // att: rows [q*128, q*128+128) from LDS, other 128 rows from global.
      // k ascending, acc = k mod 4 -> accumulation order verbatim R13.
      int l = (q << 8) + tid;
      float a0 = 0, a1 = 0, a2 = 0, a3 = 0;
      if (q == 0) {
#pragma unroll 2
        for (int k = 0; k < 128; k += 4) {
          float t0 = tanhf(sinp[k]     + sctx[k * 256 + tid]);
          float t1 = tanhf(sinp[k + 1] + sctx[(k + 1) * 256 + tid]);
          float t2 = tanhf(sinp[k + 2] + sctx[(k + 2) * 256 + tid]);
          float t3 = tanhf(sinp[k + 3] + sctx[(k + 3) * 256 + tid]);
          a0 = fmaf(sV[k], t0, a0);     a1 = fmaf(sV[k + 1], t1, a1);
          a2 = fmaf(sV[k + 2], t2, a2); a3 = fmaf(sV[k + 3], t3, a3);
        }
#pragma unroll 2
        for (int k = 128; k < H_; k += 4) {
          float t0 = tanhf(sinp[k]     + ctb[(size_t)k * L_ + l]);
          float t1 = tanhf(sinp[k + 1] + ctb[(size_t)(k + 1) * L_ + l]);
          float t2 = tanhf(sinp[k + 2] + ctb[(size_t)(k + 2) * L_ + l]);
          float t3 = tanhf(sinp[k + 3] + ctb[(size_t)(k + 3) * L_ + l]);
          a0 = fmaf(sV[k], t0, a0);     a1 = fmaf(sV[k + 1], t1, a1);
          a2 = fmaf(sV[k + 2], t2, a2); a3 = fmaf(sV[k + 3], t3, a3);
        }
      } else {
#pragma unroll 2
        for (int k = 0; k < 128; k += 4) {
          float t0 = tanhf(sinp[k]     + ctb[(size_t)k * L_ + l]);
          float t1 = tanhf(sinp[k + 1] + ctb[(size_t)(k + 1) * L_ + l]);
          float t2 = tanhf(sinp[k + 2] + ctb[(size_t)(k + 2) * L_ + l]);
          float t3 = tanhf(sinp[k + 3] + ctb[(size_t)(k + 3) * L_ + l]);
          a0 = fmaf(sV[k], t0, a0);     a1 = fmaf(sV[k + 1], t1, a1);
          a2 = fmaf(sV[k + 2], t2, a2); a3 = fmaf(sV[k + 3], t3, a3);
        }
#pragma unroll 2
        for (int k = 128; k < H_; k += 4) {
          float t0 = tanhf(sinp[k]     + sctx[(k - 128) * 256 + tid]);
          float t1 = tanhf(sinp[k + 1] + sctx[(k - 127) * 256 + tid]);
          float t2 = tanhf(sinp[k + 2] + sctx[(k - 126) * 256 + tid]);
          float t3 = tanhf(sinp[k + 3] + sctx[(k - 125) * 256 + tid]);
          a0 = fmaf(sV[k], t0, a0);     a1 = fmaf(sV[k + 1], t1, a1);
          a2 = fmaf(sV[k + 2], t2, a2); a3 = fmaf(sV[k + 3], t3, a3);
        }
      }
      float av = (a0 + a1) + (a2 + a3);
      DVSTORE(att_ws + b * L_ + l, (smask[l] > 0.0f) ? av : -__builtin_inff());
    }
    pair_sync(c0p + 1, 2u * (unsigned)(t + 1));

    // ---- P3: softmax + sample (verbatim, redundant) + hs slot-split
    float attl = DVLOAD(att_ws + b * L_ + tid);
    {
      float v = attl;
      for (int o = 32; o > 0; o >>= 1) v = fmaxf(v, __shfl_xor(v, o, 64));
      if (lane == 0) redp[wid] = v;
      __syncthreads();
      if (tid == 0) {
        float m = redp[0];
#pragma unroll
        for (int w = 1; w < 8; ++w) m = fmaxf(m, redp[w]);
        red_res = m;
      }
      __syncthreads();
    }
    float m = red_res;
    float e = expf(attl - m);
    {
      float v = e;
      for (int o = 32; o > 0; o >>= 1) v += __shfl_xor(v, o, 64);
      if (lane == 0) redp[wid] = v;
      __syncthreads();
      if (tid == 0)
        red_res = ((redp[0] + redp[1]) + (redp[2] + redp[3])) +
                  ((redp[4] + redp[5]) + (redp[6] + redp[7]));
      __syncthreads();
    }
    float S = red_res;
    float al = e / S;
    salpha[tid] = al;
    if (q == 0)
      __builtin_nontemporal_store(al, outA + (size_t)t * L_ + tid);
    float mval = smask[tid];
    __syncthreads();

    {
      uint32_t k0, k1;
      step_key(t, k0, k1);
      float g = gumbel_for(k0, k1, (uint32_t)(b * L_ + tid));
      float pl = al * mval;
      float sv = logf(pl) + g;
      int si = tid;
      for (int o = 32; o > 0; o >>= 1) {
        float ov = __shfl_xor(sv, o, 64);
        int oi = __shfl_xor(si, o, 64);
        if (ov > sv || (ov == sv && oi < si)) { sv = ov; si = oi; }
      }
      if (lane == 0) { redp[wid] = sv; redpi[wid] = si; }
      __syncthreads();
      if (tid == 0) {
        float bv = redp[0];
        int bi = redpi[0];
#pragma unroll
        for (int w = 1; w < 8; ++w) {
          if (redp[w] > bv || (redp[w] == bv && redpi[w] < bi)) {
            bv = redp[w]; bi = redpi[w];
          }
        }
        red_resi = bi;
        smask[bi] = 0.0f;
        if (q == 0) outP[t] = (float)bi;
      }
      __syncthreads();
    }
    int idx = red_resi;
    if (tid < E_) sx[tid] = embedded[((size_t)b * L_ + idx) * E_ + tid];

    // hs: 16 wave-slots over pair; block q's rows are exactly
    // [q*128, q*128+128) -> own-l chunks from LDS for BOTH blocks.
    // fma order per k verbatim -> bit-exact.
    {
      int slot = (q << 3) | wid;
      int owid = slot >> 1;
      int m0 = (slot & 1) << 4;
      for (int mm = m0; mm < m0 + 16; ++mm) {
        int k = owid * 32 + mm;          // k in [q*128, q*128+128)
        const float* cr = ctb + (size_t)k * L_;
        const float* srow = sctx + (size_t)(k - (q << 7)) * 256;
        float cv[8];
#pragma unroll
        for (int cch = 0; cch < 8; ++cch) {
          int l = lane + (cch << 6);
          cv[cch] = ((cch >> 2) == q) ? srow[l & 255] : cr[l];
        }
        float a = 0;
#pragma unroll
        for (int cch = 0; cch < 8; ++cch) {
          int l = lane + (cch << 6);
          a = fmaf(salpha[l], cv[cch], a);
        }
        for (int o = 32; o > 0; o >>= 1) a += __shfl_xor(a, o, 64);
        if (lane == 0) DVSTORE(hs_ws + b * H_ + k, a);
      }
    }
    pair_sync(c0p + 2, 2u * (unsigned)(t + 1));

    // ---- P4: h_new (verbatim round-6 double 4-acc, redundant per block)
    if (tid < H_) shs[tid] = DVLOAD(hs_ws + b * H_ + tid);
    __syncthreads();
    if (tid < H_) {
      float a0 = 0, a1 = 0, a2 = 0, a3 = 0;
#pragma unroll 4
      for (int r = 0; r < H_; r += 4) {
        a0 = fmaf(shs[r],     Wout[(size_t)r * H_ + tid],       a0);
        a1 = fmaf(shs[r + 1], Wout[(size_t)(r + 1) * H_ + tid], a1);
        a2 = fmaf(shs[r + 2], Wout[(size_t)(r + 2) * H_ + tid], a2);
        a3 = fmaf(shs[r + 3], Wout[(size_t)(r + 3) * H_ + tid], a3);
      }
#pragma unroll 4
      for (int r = 0; r < H_; r += 4) {
        a0 = fmaf(sht[r],     Wout[(size_t)(H_ + r) * H_ + tid],     a0);
        a1 = fmaf(sht[r + 1], Wout[(size_t)(H_ + r + 1) * H_ + tid], a1);
        a2 = fmaf(sht[r + 2], Wout[(size_t)(H_ + r + 2) * H_ + tid], a2);
        a3 = fmaf(sht[r + 3], Wout[(size_t)(H_ + r + 3) * H_ + tid], a3);
      }
      float hn = tanhf((((a0 + a1) + (a2 + a3))) + bout_r);
      sh[tid] = hn;
      if (q == 0 && t == L_ - 1) {
        outH[tid] = hn;
        outC[tid] = sc[tid];
      }
    }
    __syncthreads();
  }
}

// ---------------------------------------------------------------------------
// Fallback kernels (round-3 multi-kernel path, verbatim)
// ---------------------------------------------------------------------------
__global__ __launch_bounds__(512) void k_init(
    const float* __restrict__ h0, const float* __restrict__ c0,
    const float* __restrict__ dec, float* __restrict__ h,
    float* __restrict__ c, float* __restrict__ mk, float* __restrict__ x) {
  int b = blockIdx.x, tid = threadIdx.x;
  if (tid < H_) { h[b * H_ + tid] = h0[b * H_ + tid]; c[b * H_ + tid] = c0[b * H_ + tid]; }
  if (tid < E_) x[b * E_ + tid] = dec[b * E_ + tid];
  mk[b * L_ + tid] = 1.0f;
}

__global__ __launch_bounds__(256) void k_gates(
    const float* __restrict__ Wih, const float* __restrict__ bih,
    const float* __restrict__ Whh, const float* __restrict__ bhh,
    const float* __restrict__ x, const float* __restrict__ h,
    float* __restrict__ gates) {
  __shared__ float sx[E_], sh[H_];
  int b = blockIdx.x >> 2;
  int j = ((blockIdx.x & 3) << 8) + threadIdx.x;
  int tid = threadIdx.x;
  sh[tid] = h[b * H_ + tid];
  if (tid < E_) sx[tid] = x[b * E_ + tid];
  __syncthreads();
  float a0 = 0, a1 = 0, a2 = 0, a3 = 0;
#pragma unroll 4
  for (int k = 0; k < E_; k += 4) {
    const float* w = Wih + (size_t)k * G4_ + j;
    a0 = fmaf(sx[k],     w[0],       a0);
    a1 = fmaf(sx[k + 1], w[G4_],     a1);
    a2 = fmaf(sx[k + 2], w[2 * G4_], a2);
    a3 = fmaf(sx[k + 3], w[3 * G4_], a3);
  }
  float g0 = ((a0 + a1) + (a2 + a3)) + bih[j];
  a0 = a1 = a2 = a3 = 0.f;
#pragma unroll 4
  for (int k = 0; k < H_; k += 4) {
    const float* w = Whh + (size_t)k * G4_ + j;
    a0 = fmaf(sh[k],     w[0],       a0);
    a1 = fmaf(sh[k + 1], w[G4_],     a1);
    a2 = fmaf(sh[k + 2], w[2 * G4_], a2);
    a3 = fmaf(sh[k + 3], w[3 * G4_], a3);
  }
  gates[(size_t)b * G4_ + j] = (g0 + ((a0 + a1) + (a2 + a3))) + bhh[j];
}

__global__ __launch_bounds__(256) void k_lstm_att(
    const float* __restrict__ gates, const float* __restrict__ c_rd,
    float* __restrict__ c_wr, float* __restrict__ ht_ws,
    const float* __restrict__ Winp, const float* __restrict__ binp,
    const float* __restrict__ Vv, const float* __restrict__ ctxT,
    const float* __restrict__ mk, float* __restrict__ att_ws,
    float* __restrict__ out, int t) {
  __shared__ float sht[H_], sinp[H_], sV[H_];
  int b = blockIdx.x >> 1;
  int lh = blockIdx.x & 1;
  int tid = threadIdx.x;
  {
    float ig = gates[(size_t)b * G4_ + tid];
    float fg = gates[(size_t)b * G4_ + H_ + tid];
    float gg = gates[(size_t)b * G4_ + 2 * H_ + tid];
    float og = gates[(size_t)b * G4_ + 3 * H_ + tid];
    float ct = sigmoidf_(fg) * c_rd[b * H_ + tid] + sigmoidf_(ig) * tanhf(gg);
    float htv = sigmoidf_(og) * tanhf(ct);
    sht[tid] = htv;
    if (lh == 0) {
      c_wr[b * H_ + tid] = ct;
      ht_ws[b * H_ + tid] = htv;
      if (t == L_ - 1) {
        float* outC = out + (size_t)B_ * L_ * L_ + (size_t)B_ * L_ +
                      (size_t)B_ * H_ + (size_t)b * H_;
        outC[tid] = ct;
      }
    }
  }
  sV[tid] = Vv[tid];
  __syncthreads();
  {
    float a0 = 0, a1 = 0, a2 = 0, a3 = 0;
#pragma unroll 4
    for (int jv = 0; jv < H_; jv += 4) {
      a0 = fmaf(sht[jv],     Winp[(size_t)jv * H_ + tid],       a0);
      a1 = fmaf(sht[jv + 1], Winp[(size_t)(jv + 1) * H_ + tid], a1);
      a2 = fmaf(sht[jv + 2], Winp[(size_t)(jv + 2) * H_ + tid], a2);
      a3 = fmaf(sht[jv + 3], Winp[(size_t)(jv + 3) * H_ + tid], a3);
    }
    sinp[tid] = ((a0 + a1) + (a2 + a3)) + binp[tid];
  }
  __syncthreads();
  {
    int l = (lh << 8) + tid;
    const float* ctb = ctxT + (size_t)b * H_ * L_;
    float a0 = 0, a1 = 0, a2 = 0, a3 = 0;
#pragma unroll 2
    for (int k = 0; k < H_; k += 4) {
      float t0 = tanhf(sinp[k]     + ctb[(size_t)k * L_ + l]);
      float t1 = tanhf(sinp[k + 1] + ctb[(size_t)(k + 1) * L_ + l]);
      float t2 = tanhf(sinp[k + 2] + ctb[(size_t)(k + 2) * L_ + l]);
      float t3 = tanhf(sinp[k + 3] + ctb[(size_t)(k + 3) * L_ + l]);
      a0 = fmaf(sV[k], t0, a0);     a1 = fmaf(sV[k + 1], t1, a1);
      a2 = fmaf(sV[k + 2], t2, a2); a3 = fmaf(sV[k + 3], t3, a3);
    }
    float av = (a0 + a1) + (a2 + a3);
    att_ws[b * L_ + l] = (mk[b * L_ + l] > 0.0f) ? av : -__builtin_inff();
  }
}

__global__ __launch_bounds__(512) void k_sample(
    const float* __restrict__ att_ws, float* __restrict__ mk,
    float* __restrict__ alpha_ws, float* __restrict__ x,
    const float* __restrict__ embedded, float* __restrict__ out, int t) {
  __shared__ float redp[8];
  __shared__ int redpi[8];
  __shared__ float red_res;
  __shared__ int red_resi;
  int b = blockIdx.x, tid = threadIdx.x;
  int lane = tid & 63, wid = tid >> 6;
  float attl = att_ws[b * L_ + tid];
  {
    float v = attl;
    for (int o = 32; o > 0; o >>= 1) v = fmaxf(v, __shfl_xor(v, o, 64));
    if (lane == 0) redp[wid] = v;
    __syncthreads();
    if (tid == 0) {
      float m = redp[0];
#pragma unroll
      for (int w = 1; w < 8; ++w) m = fmaxf(m, redp[w]);
      red_res = m;
    }
    __syncthreads();
  }
  float m = red_res;
  float e = expf(attl - m);
  {
    float v = e;
    for (int o = 32; o > 0; o >>= 1) v += __shfl_xor(v, o, 64);
    if (lane == 0) redp[wid] = v;
    __syncthreads();
    if (tid == 0)
      red_res = ((redp[0] + redp[1]) + (redp[2] + redp[3])) +
                ((redp[4] + redp[5]) + (redp[6] + redp[7]));
    __syncthreads();
  }
  float S = red_res;
  float al = e / S;
  alpha_ws[b * L_ + tid] = al;
  __builtin_nontemporal_store(al, out + ((size_t)b * L_ + t) * L_ + tid);
  float mval = mk[b * L_ + tid];
  {
    uint32_t k0, k1;
    step_key(t, k0, k1);
    float g = gumbel_for(k0, k1, (uint32_t)(b * L_ + tid));
    float pl = al * mval;
    float sv = logf(pl) + g;
    int si = tid;
    for (int o = 32; o > 0; o >>= 1) {
      float ov = __shfl_xor(sv, o, 64);
      int oi = __shfl_xor(si, o, 64);
      if (ov > sv || (ov == sv && oi < si)) { sv = ov; si = oi; }
    }
    if (lane == 0) { redp[wid] = sv; redpi[wid] = si; }
    __syncthreads();
    if (tid == 0) {
      float bv = redp[0];
      int bi = redpi[0];
#pragma unroll
      for (int w = 1; w < 8; ++w) {
        if (redp[w] > bv || (redp[w] == bv && redpi[w] < bi)) {
          bv = redp[w]; bi = redpi[w];
        }
      }
      red_resi = bi;
      mk[b * L_ + bi] = 0.0f;
      out[(size_t)B_ * L_ * L_ + (size_t)b * L_ + t] = (float)bi;
    }
    __syncthreads();
  }
  int idx = red_resi;
  if (tid < E_) x[b * E_ + tid] = embedded[((size_t)b * L_ + idx) * E_ + tid];
}

__global__ __launch_bounds__(256) void k_hs(
    const float* __restrict__ alpha_ws, const float* __restrict__ ctxT,
    float* __restrict__ hs_ws) {
  __shared__ float salpha[L_];
  int b = blockIdx.x >> 1;
  int kh = blockIdx.x & 1;
  int tid = threadIdx.x;
  int lane = tid & 63, wid = tid >> 6;
  salpha[tid] = alpha_ws[b * L_ + tid];
  salpha[tid + 256] = alpha_ws[b * L_ + tid + 256];
  __syncthreads();
  const float* ctb = ctxT + (size_t)b * H_ * L_;
  for (int mm = 0; mm < 32; ++mm) {
    int k = (kh * 4 + wid) * 32 + mm;
    const float* cr = ctb + (size_t)k * L_;
    float a = 0;
#pragma unroll
    for (int cch = 0; cch < 8; ++cch) {
      int l = lane + (cch << 6);
      a = fmaf(salpha[l], cr[l], a);
    }
    for (int o = 32; o > 0; o >>= 1) a += __shfl_xor(a, o, 64);
    if (lane == 0) hs_ws[b * H_ + k] = a;
  }
}

__global__ __launch_bounds__(256) void k_hnew(
    const float* __restrict__ hs_ws, const float* __restrict__ ht_ws,
    const float* __restrict__ Wout, const float* __restrict__ bout,
    float* __restrict__ h, float* __restrict__ out, int t) {
  __shared__ float shs[H_], sht[H_];
  int b = blockIdx.x, tid = threadIdx.x;
  shs[tid] = hs_ws[b * H_ + tid];
  sht[tid] = ht_ws[b * H_ + tid];
  __syncthreads();
  float a0 = 0, a1 = 0, a2 = 0, a3 = 0;
#pragma unroll 4
  for (int r = 0; r < H_; r += 4) {
    a0 = fmaf(shs[r],     Wout[(size_t)r * H_ + tid],       a0);
    a1 = fmaf(shs[r + 1], Wout[(size_t)(r + 1) * H_ + tid], a1);
    a2 = fmaf(shs[r + 2], Wout[(size_t)(r + 2) * H_ + tid], a2);
    a3 = fmaf(shs[r + 3], Wout[(size_t)(r + 3) * H_ + tid], a3);
  }
#pragma unroll 4
  for (int r = 0; r < H_; r += 4) {
    a0 = fmaf(sht[r],     Wout[(size_t)(H_ + r) * H_ + tid],     a0);
    a1 = fmaf(sht[r + 1], Wout[(size_t)(H_ + r + 1) * H_ + tid], a1);
    a2 = fmaf(sht[r + 2], Wout[(size_t)(H_ + r + 2) * H_ + tid], a2);
    a3 = fmaf(sht[r + 3], Wout[(size_t)(H_ + r + 3) * H_ + tid], a3);
  }
  float hn = tanhf((((a0 + a1) + (a2 + a3))) + bout[tid]);
  h[b * H_ + tid] = hn;
  if (t == L_ - 1) {
    float* outH = out + (size_t)B_ * L_ * L_ + (size_t)B_ * L_ + (size_t)b * H_;
    outH[tid] = hn;
  }
}

// ---------------------------------------------------------------------------
extern "C" void kernel_launch(void* const* d_in, const int* in_sizes, int n_in,
                              void* d_out, int out_size, void* d_ws, size_t ws_size,
                              hipStream_t stream) {
  const float* embedded = (const float*)d_in[0];
  const float* dec      = (const float*)d_in[1];
  const float* h0       = (const float*)d_in[2];
  const float* c0in     = (const float*)d_in[3];
  const float* context  = (const float*)d_in[4];
  const float* Wih      = (const float*)d_in[5];
  const float* bih      = (const float*)d_in[6];
  const float* Whh      = (const float*)d_in[7];
  const float* bhh      = (const float*)d_in[8];
  const float* Wout     = (const float*)d_in[9];
  const float* bout     = (const float*)d_in[10];
  const float* Winp     = (const float*)d_in[11];
  const float* binp     = (const float*)d_in[12];
  const float* Wctx     = (const float*)d_in[13];
  const float* bctx     = (const float*)d_in[14];
  const float* V        = (const float*)d_in[15];
  float* out = (float*)d_out;

  float* ws = (float*)d_ws;
  const size_t CTXF = (size_t)B_ * H_ * L_;   // 64 MB
  float* ctxT  = ws;
  float* gates = ctxT + CTXF;                 // 131072
  float* hbuf  = gates + (size_t)B_ * G4_;    // 32768 (fallback)
  float* cb0   = hbuf + (size_t)B_ * H_;      // 32768 (fallback)
  float* cb1   = cb0 + (size_t)B_ * H_;       // 32768 (fallback)
  float* htb   = cb1 + (size_t)B_ * H_;       // 32768 (fallback)
  float* xb    = htb + (size_t)B_ * H_;       // 16384 (fallback)
  float* attb  = xb + (size_t)B_ * E_;        // 65536
  float* alb   = attb + (size_t)B_ * L_;      // 65536 (fallback alpha; coop cnt)
  float* mkb   = alb + (size_t)B_ * L_;       // 65536 (fallback)
  float* hsb   = mkb + (size_t)B_ * L_;       // 32768
  unsigned* cnt = (unsigned*)alb;             // 4096 words used (coop only)
  size_t need_f = (size_t)(hsb + (size_t)B_ * H_ - ws);
  size_t need_bytes = need_f * sizeof(float);

  if (ws_size < need_bytes) return;

  ctx_precompute<<<dim3(B_ * 8), dim3(256), 0, stream>>>(context, Wctx, bctx, ctxT, cnt);

  void* args[] = {
    (void*)&embedded, (void*)&dec, (void*)&h0, (void*)&c0in,
    (void*)&Wih, (void*)&bih, (void*)&Whh, (void*)&bhh,
    (void*)&Wout, (void*)&bout, (void*)&Winp, (void*)&binp,
    (void*)&V, (void*)&ctxT, (void*)&gates, (void*)&attb,
    (void*)&hsb, (void*)&cnt, (void*)&out };
  hipError_t e = hipLaunchCooperativeKernel(
      (const void*)coop_scan, dim3(B_ * 2), dim3(512), args,
      128 * 256 * sizeof(float) /* 128 KB dynamic LDS ctx tile */, stream);

  if (e != hipSuccess) {
    // fallback: round-3 multi-kernel path (passed, 78 ms)
    k_init<<<dim3(B_), dim3(512), 0, stream>>>(h0, c0in, dec, hbuf, cb0, mkb, xb);
    for (int t = 0; t < L_; ++t) {
      float* crd = (t & 1) ? cb1 : cb0;
      float* cwr = (t & 1) ? cb0 : cb1;
      k_gates<<<dim3(B_ * 4), dim3(256), 0, stream>>>(Wih, bih, Whh, bhh, xb, hbuf, gates);
      k_lstm_att<<<dim3(B_ * 2), dim3(256), 0, stream>>>(
          gates, crd, cwr, htb, Winp, binp, V, ctxT, mkb, attb, out, t);
      k_sample<<<dim3(B_), dim3(512), 0, stream>>>(attb, mkb, alb, xb, embedded, out, t);
      k_hs<<<dim3(B_ * 2), dim3(256), 0, stream>>>(alb, ctxT, hsb);
      k_hnew<<<dim3(B_), dim3(256), 0, stream>>>(hsb, htb, Wout, bout, hbuf, out, t);
    }
  }
}

// Round 15
// 49332.468 us; speedup vs baseline: 1.0521x; 1.0521x over previous
//
#include <hip/hip_runtime.h>
#include <hip/hip_bf16.h>
#include <stdint.h>

// ---------------------------------------------------------------------------
// Pointer-network decoder: persistent pair-synced kernel, fence-free.
// Round-14 structure VERBATIM (steady ~49.6ms, replay-proven bit-exact) + ONE
// change: ctx LDS tile extended 128->144 rows (uses the spare 21KB of LDS;
// 144KB dynamic + ~11KB static = 155KB <= 160KB, still 1 block/CU).
//   q=0 tile rows [0,144), q=1 tile rows [112,256) -- hs rows [q*128,+128)
//   remain fully covered; att's global-row count drops 128 -> 112.
// Pure source redirection: same bytes, same k-ascending 4-acc order, same
// syncs -> bit-identical pointer trajectory.
// Fallback: round-3 multi-kernel path (passed, 78 ms).
// ---------------------------------------------------------------------------

#define PARTITIONABLE 1

#define B_ 128
#define L_ 512
#define E_ 128
#define H_ 256
#define G4_ 1024
#define CNT_STRIDE 32   // words per pair: one 128B line, no false sharing
#define TROWS 144       // LDS tile rows
#define TBASE1 112      // q=1 tile base row (256-144)

#define DVLOAD(p)     __hip_atomic_load((p), __ATOMIC_RELAXED, __HIP_MEMORY_SCOPE_AGENT)
#define DVSTORE(p, v) __hip_atomic_store((p), (v), __ATOMIC_RELAXED, __HIP_MEMORY_SCOPE_AGENT)

// ---------------- Threefry-2x32 (exact JAX reproduction) -------------------
__device__ __forceinline__ void tf2x32(uint32_t k0, uint32_t k1,
                                       uint32_t x0, uint32_t x1,
                                       uint32_t &o0, uint32_t &o1) {
  uint32_t ks2 = k0 ^ k1 ^ 0x1BD11BDAu;
#define TFR(a, b, r) { a += b; b = (b << (r)) | (b >> (32 - (r))); b ^= a; }
  x0 += k0; x1 += k1;
  TFR(x0, x1, 13) TFR(x0, x1, 15) TFR(x0, x1, 26) TFR(x0, x1, 6)
  x0 += k1; x1 += ks2 + 1u;
  TFR(x0, x1, 17) TFR(x0, x1, 29) TFR(x0, x1, 16) TFR(x0, x1, 24)
  x0 += ks2; x1 += k0 + 2u;
  TFR(x0, x1, 13) TFR(x0, x1, 15) TFR(x0, x1, 26) TFR(x0, x1, 6)
  x0 += k0; x1 += k1 + 3u;
  TFR(x0, x1, 17) TFR(x0, x1, 29) TFR(x0, x1, 16) TFR(x0, x1, 24)
  x0 += k1; x1 += ks2 + 4u;
  TFR(x0, x1, 13) TFR(x0, x1, 15) TFR(x0, x1, 26) TFR(x0, x1, 6)
  x0 += ks2; x1 += k0 + 5u;
#undef TFR
  o0 = x0; o1 = x1;
}

__device__ __forceinline__ void step_key(int t, uint32_t &k0, uint32_t &k1) {
#if PARTITIONABLE
  tf2x32(0u, 42u, 0u, (uint32_t)t, k0, k1);
#else
  uint32_t d0, d1;
  uint32_t i = 2u * (uint32_t)t;
  if (t < 256) {
    tf2x32(0u, 42u, i,      512u + i, k0, d1);
    tf2x32(0u, 42u, i + 1u, 513u + i, k1, d1);
  } else {
    tf2x32(0u, 42u, i - 512u, i,      d0, k0);
    tf2x32(0u, 42u, i - 511u, i + 1u, d0, k1);
  }
#endif
}

__device__ __forceinline__ float gumbel_for(uint32_t k0, uint32_t k1, uint32_t j) {
  uint32_t bits, o0, o1;
#if PARTITIONABLE
  tf2x32(k0, k1, 0u, j, o0, o1);
  bits = o0 ^ o1;
#else
  if (j < 32768u) { tf2x32(k0, k1, j, j + 32768u, o0, o1); bits = o0; }
  else            { tf2x32(k0, k1, j - 32768u, j, o0, o1); bits = o1; }
#endif
  float f = __uint_as_float((bits >> 9) | 0x3f800000u) - 1.0f;
  float u = (f > 0.0f) ? f : 1.1754943508222875e-38f;
  return -logf(-logf(u));
}

__device__ __forceinline__ float sigmoidf_(float x) {
  return 1.0f / (1.0f + expf(-x));
}

// ---------------------------------------------------------------------------
// ctx precompute + pair-sync-counter init (replay-safe: runs every launch)
// ---------------------------------------------------------------------------
__global__ __launch_bounds__(256, 2) void ctx_precompute(
    const float* __restrict__ context, const float* __restrict__ Wctx,
    const float* __restrict__ bctx, float* __restrict__ ctxT,
    unsigned* __restrict__ cnt) {
  __shared__ float lctx[64][256];
  if (blockIdx.x == 0) {
    for (int i = threadIdx.x; i < B_ * CNT_STRIDE; i += 256) cnt[i] = 0u;
  }
  int b = blockIdx.x >> 3;
  int l0 = (blockIdx.x & 7) << 6;
  const float* src = context + ((size_t)b * L_ + l0) * H_;
  for (int i = threadIdx.x; i < 64 * 256; i += 256)
    lctx[i >> 8][i & 255] = src[i];
  __syncthreads();
  int k = threadIdx.x;
  float bk = bctx[k];
  for (int g = 0; g < 8; ++g) {
    float acc[8] = {0, 0, 0, 0, 0, 0, 0, 0};
    for (int j = 0; j < H_; ++j) {
      float w = Wctx[(size_t)j * H_ + k];
#pragma unroll
      for (int i = 0; i < 8; ++i) acc[i] = fmaf(lctx[g * 8 + i][j], w, acc[i]);
    }
    float* dst = ctxT + ((size_t)b * H_ + k) * L_ + l0 + g * 8;
#pragma unroll
    for (int i = 0; i < 8; ++i) dst[i] = acc[i] + bk;
  }
}

// ---------------------------------------------------------------------------
// fence-free pair sync (protocol proven bit-exact in rounds 5/6/9/13/14)
// ---------------------------------------------------------------------------
__device__ __forceinline__ void pair_sync(unsigned* c, unsigned target) {
  __syncthreads();   // drains vmcnt before barrier -> stores visible
  if (threadIdx.x == 0) {
    __hip_atomic_fetch_add(c, 1u, __ATOMIC_RELAXED, __HIP_MEMORY_SCOPE_AGENT);
    while (__hip_atomic_load(c, __ATOMIC_RELAXED, __HIP_MEMORY_SCOPE_AGENT) < target)
      __builtin_amdgcn_s_sleep(1);
  }
  __syncthreads();
}

// ---------------------------------------------------------------------------
// Persistent pair-synced scan: pair (b, b+128), q = blockIdx>>7.
// Dynamic LDS: sctx[TROWS][256] = ctxT[rows base..base+144)[own l-half],
// base = q==0 ? 0 : 112.
// ---------------------------------------------------------------------------
__global__ __launch_bounds__(512, 1) void coop_scan(
    const float* __restrict__ embedded, const float* __restrict__ dec_in,
    const float* __restrict__ h0, const float* __restrict__ c0,
    const float* __restrict__ Wih, const float* __restrict__ bih,
    const float* __restrict__ Whh, const float* __restrict__ bhh,
    const float* __restrict__ Wout, const float* __restrict__ bout,
    const float* __restrict__ Winp, const float* __restrict__ binp,
    const float* __restrict__ Vv, const float* __restrict__ ctxT,
    float* __restrict__ gates_ws, float* __restrict__ att_ws,
    float* __restrict__ hs_ws, unsigned* __restrict__ cnt,
    float* __restrict__ out) {
  extern __shared__ float sctx[];   // [TROWS][256]
  __shared__ float sh[H_], sc[H_], sht[H_], sx[E_], sinp[H_], shs[H_];
  __shared__ float salpha[L_], smask[L_];
  __shared__ float sV[H_];
  __shared__ float redp[8];
  __shared__ int redpi[8];
  __shared__ float red_res;
  __shared__ int red_resi;

  const int tid = threadIdx.x;
  const int b = blockIdx.x & 127;
  const int q = blockIdx.x >> 7;
  const int lane = tid & 63, wid = tid >> 6;
  const int tbase = q ? TBASE1 : 0;

  if (tid < H_) {
    sh[tid] = h0[b * H_ + tid];
    sc[tid] = c0[b * H_ + tid];
    sV[tid] = Vv[tid];
  }
  if (tid < E_) sx[tid] = dec_in[b * E_ + tid];
  smask[tid] = 1.0f;

  const float* ctb = ctxT + (size_t)b * H_ * L_;
  // preload LDS ctx tile: rows k in [tbase, tbase+144), l in [q*256, +256)
  for (int i = tid; i < TROWS * 256; i += 512)
    sctx[i] = ctb[(size_t)(tbase + (i >> 8)) * L_ + (q << 8) + (i & 255)];
  __syncthreads();

  float* outA = out + (size_t)b * L_ * L_;
  float* outP = out + (size_t)B_ * L_ * L_ + (size_t)b * L_;
  float* outH = out + (size_t)B_ * L_ * L_ + (size_t)B_ * L_ + (size_t)b * H_;
  float* outC = outH + (size_t)B_ * H_;
  unsigned* c0p = cnt + b * CNT_STRIDE;   // one 128B line per pair

  const int jP1 = (q << 9) + tid;          // this thread's gate column
  const float bihj = bih[jP1], bhhj = bhh[jP1];
  const float binp_r = (tid < H_) ? binp[tid] : 0.0f;
  const float bout_r = (tid < H_) ? bout[tid] : 0.0f;

  for (int t = 0; t < L_; ++t) {
    // ---- P1: gates[b][j] (verbatim round-6)
    {
      int j = jP1;
      float a0 = 0, a1 = 0, a2 = 0, a3 = 0;
#pragma unroll 4
      for (int k = 0; k < E_; k += 4) {
        const float* w = Wih + (size_t)k * G4_ + j;
        a0 = fmaf(sx[k],     w[0],       a0);
        a1 = fmaf(sx[k + 1], w[G4_],     a1);
        a2 = fmaf(sx[k + 2], w[2 * G4_], a2);
        a3 = fmaf(sx[k + 3], w[3 * G4_], a3);
      }
      float g0 = ((a0 + a1) + (a2 + a3)) + bihj;
      a0 = a1 = a2 = a3 = 0.f;
#pragma unroll 4
      for (int k = 0; k < H_; k += 4) {
        const float* w = Whh + (size_t)k * G4_ + j;
        a0 = fmaf(sh[k],     w[0],       a0);
        a1 = fmaf(sh[k + 1], w[G4_],     a1);
        a2 = fmaf(sh[k + 2], w[2 * G4_], a2);
        a3 = fmaf(sh[k + 3], w[3 * G4_], a3);
      }
      DVSTORE(gates_ws + (size_t)b * G4_ + j, (g0 + ((a0 + a1) + (a2 + a3))) + bhhj);
    }
    pair_sync(c0p + 0, 2u * (unsigned)(t + 1));

    // ---- P2: LSTM pointwise + inp GEMV (redundant) + att own l-half
    if (tid < H_) {
      float ig = DVLOAD(gates_ws + (size_t)b * G4_ + tid);
      float fg = DVLOAD(gates_ws + (size_t)b * G4_ + H_ + tid);
      float gg = DVLOAD(gates_ws + (size_t)b * G4_ + 2 * H_ + tid);
      float og = DVLOAD(gates_ws + (size_t)b * G4_ + 3 * H_ + tid);
      float ct = sigmoidf_(fg) * sc[tid] + sigmoidf_(ig) * tanhf(gg);
      float htv = sigmoidf_(og) * tanhf(ct);
      sc[tid] = ct;
      sht[tid] = htv;
    }
    __syncthreads();
    if (tid < H_) {
      float a0 = 0, a1 = 0, a2 = 0, a3 = 0;
#pragma unroll 4
      for (int jv = 0; jv < H_; jv += 4) {
        a0 = fmaf(sht[jv],     Winp[(size_t)jv * H_ + tid],       a0);
        a1 = fmaf(sht[jv + 1], Winp[(size_t)(jv + 1) * H_ + tid], a1);
        a2 = fmaf(sht[jv + 2], Winp[(size_t)(jv + 2) * H_ + tid], a2);
        a3 = fmaf(sht[jv + 3], Winp[(size_t)(jv + 3) * H_ + tid], a3);
      }
      sinp[tid] = ((a0 + a1) + (a2 + a3)) + binp_r;
    }
    __syncthreads();
    if (tid < H_) {
      // att: tile rows from LDS, remaining rows from global.
      // k ascending, acc = k mod 4 -> accumulation order verbatim R14.
      int l = (q << 8) + tid;
      float a0 = 0, a1 = 0, a2 = 0, a3 = 0;
      if (q == 0) {
#pragma unroll 2
        for (int k = 0; k < TROWS; k += 4) {
          float t0 = tanhf(sinp[k]     + sctx[k * 256 + tid]);
          float t1 = tanhf(sinp[k + 1] + sctx[(k + 1) * 256 + tid]);
          float t2 = tanhf(sinp[k + 2] + sctx[(k + 2) * 256 + tid]);
          float t3 = tanhf(sinp[k + 3] + sctx[(k + 3) * 256 + tid]);
          a0 = fmaf(sV[k], t0, a0);     a1 = fmaf(sV[k + 1], t1, a1);
          a2 = fmaf(sV[k + 2], t2, a2); a3 = fmaf(sV[k + 3], t3, a3);
        }
#pragma unroll 2
        for (int k = TROWS; k < H_; k += 4) {
          float t0 = tanhf(sinp[k]     + ctb[(size_t)k * L_ + l]);
          float t1 = tanhf(sinp[k + 1] + ctb[(size_t)(k + 1) * L_ + l]);
          float t2 = tanhf(sinp[k + 2] + ctb[(size_t)(k + 2) * L_ + l]);
          float t3 = tanhf(sinp[k + 3] + ctb[(size_t)(k + 3) * L_ + l]);
          a0 = fmaf(sV[k], t0, a0);     a1 = fmaf(sV[k + 1], t1, a1);
          a2 = fmaf(sV[k + 2], t2, a2); a3 = fmaf(sV[k + 3], t3, a3);
        }
      } else {
#pragma unroll 2
        for (int k = 0; k < TBASE1; k += 4) {
          float t0 = tanhf(sinp[k]     + ctb[(size_t)k * L_ + l]);
          float t1 = tanhf(sinp[k + 1] + ctb[(size_t)(k + 1) * L_ + l]);
          float t2 = tanhf(sinp[k + 2] + ctb[(size_t)(k + 2) * L_ + l]);
          float t3 = tanhf(sinp[k + 3] + ctb[(size_t)(k + 3) * L_ + l]);
          a0 = fmaf(sV[k], t0, a0);     a1 = fmaf(sV[k + 1], t1, a1);
          a2 = fmaf(sV[k + 2], t2, a2); a3 = fmaf(sV[k + 3], t3, a3);
        }
#pragma unroll 2
        for (int k = TBASE1; k < H_; k += 4) {
          float t0 = tanhf(sinp[k]     + sctx[(k - TBASE1) * 256 + tid]);
          float t1 = tanhf(sinp[k + 1] + sctx[(k - TBASE1 + 1) * 256 + tid]);
          float t2 = tanhf(sinp[k + 2] + sctx[(k - TBASE1 + 2) * 256 + tid]);
          float t3 = tanhf(sinp[k + 3] + sctx[(k - TBASE1 + 3) * 256 + tid]);
          a0 = fmaf(sV[k], t0, a0);     a1 = fmaf(sV[k + 1], t1, a1);
          a2 = fmaf(sV[k + 2], t2, a2); a3 = fmaf(sV[k + 3], t3, a3);
        }
      }
      float av = (a0 + a1) + (a2 + a3);
      DVSTORE(att_ws + b * L_ + l, (smask[l] > 0.0f) ? av : -__builtin_inff());
    }
    pair_sync(c0p + 1, 2u * (unsigned)(t + 1));

    // ---- P3: softmax + sample (verbatim, redundant) + hs slot-split
    float attl = DVLOAD(att_ws + b * L_ + tid);
    {
      float v = attl;
      for (int o = 32; o > 0; o >>= 1) v = fmaxf(v, __shfl_xor(v, o, 64));
      if (lane == 0) redp[wid] = v;
      __syncthreads();
      if (tid == 0) {
        float m = redp[0];
#pragma unroll
        for (int w = 1; w < 8; ++w) m = fmaxf(m, redp[w]);
        red_res = m;
      }
      __syncthreads();
    }
    float m = red_res;
    float e = expf(attl - m);
    {
      float v = e;
      for (int o = 32; o > 0; o >>= 1) v += __shfl_xor(v, o, 64);
      if (lane == 0) redp[wid] = v;
      __syncthreads();
      if (tid == 0)
        red_res = ((redp[0] + redp[1]) + (redp[2] + redp[3])) +
                  ((redp[4] + redp[5]) + (redp[6] + redp[7]));
      __syncthreads();
    }
    float S = red_res;
    float al = e / S;
    salpha[tid] = al;
    if (q == 0)
      __builtin_nontemporal_store(al, outA + (size_t)t * L_ + tid);
    float mval = smask[tid];
    __syncthreads();

    {
      uint32_t k0, k1;
      step_key(t, k0, k1);
      float g = gumbel_for(k0, k1, (uint32_t)(b * L_ + tid));
      float pl = al * mval;
      float sv = logf(pl) + g;
      int si = tid;
      for (int o = 32; o > 0; o >>= 1) {
        float ov = __shfl_xor(sv, o, 64);
        int oi = __shfl_xor(si, o, 64);
        if (ov > sv || (ov == sv && oi < si)) { sv = ov; si = oi; }
      }
      if (lane == 0) { redp[wid] = sv; redpi[wid] = si; }
      __syncthreads();
      if (tid == 0) {
        float bv = redp[0];
        int bi = redpi[0];
#pragma unroll
        for (int w = 1; w < 8; ++w) {
          if (redp[w] > bv || (redp[w] == bv && redpi[w] < bi)) {
            bv = redp[w]; bi = redpi[w];
          }
        }
        red_resi = bi;
        smask[bi] = 0.0f;
        if (q == 0) outP[t] = (float)bi;
      }
      __syncthreads();
    }
    int idx = red_resi;
    if (tid < E_) sx[tid] = embedded[((size_t)b * L_ + idx) * E_ + tid];

    // hs: 16 wave-slots over pair; block q's rows [q*128,+128) are inside
    // the tile -> own-l chunks from LDS for BOTH blocks. fma order verbatim.
    {
      int slot = (q << 3) | wid;
      int owid = slot >> 1;
      int m0 = (slot & 1) << 4;
      for (int mm = m0; mm < m0 + 16; ++mm) {
        int k = owid * 32 + mm;          // k in [q*128, q*128+128)
        const float* cr = ctb + (size_t)k * L_;
        const float* srow = sctx + (size_t)(k - tbase) * 256;
        float cv[8];
#pragma unroll
        for (int cch = 0; cch < 8; ++cch) {
          int l = lane + (cch << 6);
          cv[cch] = ((cch >> 2) == q) ? srow[l & 255] : cr[l];
        }
        float a = 0;
#pragma unroll
        for (int cch = 0; cch < 8; ++cch) {
          int l = lane + (cch << 6);
          a = fmaf(salpha[l], cv[cch], a);
        }
        for (int o = 32; o > 0; o >>= 1) a += __shfl_xor(a, o, 64);
        if (lane == 0) DVSTORE(hs_ws + b * H_ + k, a);
      }
    }
    pair_sync(c0p + 2, 2u * (unsigned)(t + 1));

    // ---- P4: h_new (verbatim round-6 double 4-acc, redundant per block)
    if (tid < H_) shs[tid] = DVLOAD(hs_ws + b * H_ + tid);
    __syncthreads();
    if (tid < H_) {
      float a0 = 0, a1 = 0, a2 = 0, a3 = 0;
#pragma unroll 4
      for (int r = 0; r < H_; r += 4) {
        a0 = fmaf(shs[r],     Wout[(size_t)r * H_ + tid],       a0);
        a1 = fmaf(shs[r + 1], Wout[(size_t)(r + 1) * H_ + tid], a1);
        a2 = fmaf(shs[r + 2], Wout[(size_t)(r + 2) * H_ + tid], a2);
        a3 = fmaf(shs[r + 3], Wout[(size_t)(r + 3) * H_ + tid], a3);
      }
#pragma unroll 4
      for (int r = 0; r < H_; r += 4) {
        a0 = fmaf(sht[r],     Wout[(size_t)(H_ + r) * H_ + tid],     a0);
        a1 = fmaf(sht[r + 1], Wout[(size_t)(H_ + r + 1) * H_ + tid], a1);
        a2 = fmaf(sht[r + 2], Wout[(size_t)(H_ + r + 2) * H_ + tid], a2);
        a3 = fmaf(sht[r + 3], Wout[(size_t)(H_ + r + 3) * H_ + tid], a3);
      }
      float hn = tanhf((((a0 + a1) + (a2 + a3))) + bout_r);
      sh[tid] = hn;
      if (q == 0 && t == L_ - 1) {
        outH[tid] = hn;
        outC[tid] = sc[tid];
      }
    }
    __syncthreads();
  }
}

// ---------------------------------------------------------------------------
// Fallback kernels (round-3 multi-kernel path, verbatim)
// ---------------------------------------------------------------------------
__global__ __launch_bounds__(512) void k_init(
    const float* __restrict__ h0, const float* __restrict__ c0,
    const float* __restrict__ dec, float* __restrict__ h,
    float* __restrict__ c, float* __restrict__ mk, float* __restrict__ x) {
  int b = blockIdx.x, tid = threadIdx.x;
  if (tid < H_) { h[b * H_ + tid] = h0[b * H_ + tid]; c[b * H_ + tid] = c0[b * H_ + tid]; }
  if (tid < E_) x[b * E_ + tid] = dec[b * E_ + tid];
  mk[b * L_ + tid] = 1.0f;
}

__global__ __launch_bounds__(256) void k_gates(
    const float* __restrict__ Wih, const float* __restrict__ bih,
    const float* __restrict__ Whh, const float* __restrict__ bhh,
    const float* __restrict__ x, const float* __restrict__ h,
    float* __restrict__ gates) {
  __shared__ float sx[E_], sh[H_];
  int b = blockIdx.x >> 2;
  int j = ((blockIdx.x & 3) << 8) + threadIdx.x;
  int tid = threadIdx.x;
  sh[tid] = h[b * H_ + tid];
  if (tid < E_) sx[tid] = x[b * E_ + tid];
  __syncthreads();
  float a0 = 0, a1 = 0, a2 = 0, a3 = 0;
#pragma unroll 4
  for (int k = 0; k < E_; k += 4) {
    const float* w = Wih + (size_t)k * G4_ + j;
    a0 = fmaf(sx[k],     w[0],       a0);
    a1 = fmaf(sx[k + 1], w[G4_],     a1);
    a2 = fmaf(sx[k + 2], w[2 * G4_], a2);
    a3 = fmaf(sx[k + 3], w[3 * G4_], a3);
  }
  float g0 = ((a0 + a1) + (a2 + a3)) + bih[j];
  a0 = a1 = a2 = a3 = 0.f;
#pragma unroll 4
  for (int k = 0; k < H_; k += 4) {
    const float* w = Whh + (size_t)k * G4_ + j;
    a0 = fmaf(sh[k],     w[0],       a0);
    a1 = fmaf(sh[k + 1], w[G4_],     a1);
    a2 = fmaf(sh[k + 2], w[2 * G4_], a2);
    a3 = fmaf(sh[k + 3], w[3 * G4_], a3);
  }
  gates[(size_t)b * G4_ + j] = (g0 + ((a0 + a1) + (a2 + a3))) + bhh[j];
}

__global__ __launch_bounds__(256) void k_lstm_att(
    const float* __restrict__ gates, const float* __restrict__ c_rd,
    float* __restrict__ c_wr, float* __restrict__ ht_ws,
    const float* __restrict__ Winp, const float* __restrict__ binp,
    const float* __restrict__ Vv, const float* __restrict__ ctxT,
    const float* __restrict__ mk, float* __restrict__ att_ws,
    float* __restrict__ out, int t) {
  __shared__ float sht[H_], sinp[H_], sV[H_];
  int b = blockIdx.x >> 1;
  int lh = blockIdx.x & 1;
  int tid = threadIdx.x;
  {
    float ig = gates[(size_t)b * G4_ + tid];
    float fg = gates[(size_t)b * G4_ + H_ + tid];
    float gg = gates[(size_t)b * G4_ + 2 * H_ + tid];
    float og = gates[(size_t)b * G4_ + 3 * H_ + tid];
    float ct = sigmoidf_(fg) * c_rd[b * H_ + tid] + sigmoidf_(ig) * tanhf(gg);
    float htv = sigmoidf_(og) * tanhf(ct);
    sht[tid] = htv;
    if (lh == 0) {
      c_wr[b * H_ + tid] = ct;
      ht_ws[b * H_ + tid] = htv;
      if (t == L_ - 1) {
        float* outC = out + (size_t)B_ * L_ * L_ + (size_t)B_ * L_ +
                      (size_t)B_ * H_ + (size_t)b * H_;
        outC[tid] = ct;
      }
    }
  }
  sV[tid] = Vv[tid];
  __syncthreads();
  {
    float a0 = 0, a1 = 0, a2 = 0, a3 = 0;
#pragma unroll 4
    for (int jv = 0; jv < H_; jv += 4) {
      a0 = fmaf(sht[jv],     Winp[(size_t)jv * H_ + tid],       a0);
      a1 = fmaf(sht[jv + 1], Winp[(size_t)(jv + 1) * H_ + tid], a1);
      a2 = fmaf(sht[jv + 2], Winp[(size_t)(jv + 2) * H_ + tid], a2);
      a3 = fmaf(sht[jv + 3], Winp[(size_t)(jv + 3) * H_ + tid], a3);
    }
    sinp[tid] = ((a0 + a1) + (a2 + a3)) + binp[tid];
  }
  __syncthreads();
  {
    int l = (lh << 8) + tid;
    const float* ctb = ctxT + (size_t)b * H_ * L_;
    float a0 = 0, a1 = 0, a2 = 0, a3 = 0;
#pragma unroll 2
    for (int k = 0; k < H_; k += 4) {
      float t0 = tanhf(sinp[k]     + ctb[(size_t)k * L_ + l]);
      float t1 = tanhf(sinp[k + 1] + ctb[(size_t)(k + 1) * L_ + l]);
      float t2 = tanhf(sinp[k + 2] + ctb[(size_t)(k + 2) * L_ + l]);
      float t3 = tanhf(sinp[k + 3] + ctb[(size_t)(k + 3) * L_ + l]);
      a0 = fmaf(sV[k], t0, a0);     a1 = fmaf(sV[k + 1], t1, a1);
      a2 = fmaf(sV[k + 2], t2, a2); a3 = fmaf(sV[k + 3], t3, a3);
    }
    float av = (a0 + a1) + (a2 + a3);
    att_ws[b * L_ + l] = (mk[b * L_ + l] > 0.0f) ? av : -__builtin_inff();
  }
}

__global__ __launch_bounds__(512) void k_sample(
    const float* __restrict__ att_ws, float* __restrict__ mk,
    float* __restrict__ alpha_ws, float* __restrict__ x,
    const float* __restrict__ embedded, float* __restrict__ out, int t) {
  __shared__ float redp[8];
  __shared__ int redpi[8];
  __shared__ float red_res;
  __shared__ int red_resi;
  int b = blockIdx.x, tid = threadIdx.x;
  int lane = tid & 63, wid = tid >> 6;
  float attl = att_ws[b * L_ + tid];
  {
    float v = attl;
    for (int o = 32; o > 0; o >>= 1) v = fmaxf(v, __shfl_xor(v, o, 64));
    if (lane == 0) redp[wid] = v;
    __syncthreads();
    if (tid == 0) {
      float m = redp[0];
#pragma unroll
      for (int w = 1; w < 8; ++w) m = fmaxf(m, redp[w]);
      red_res = m;
    }
    __syncthreads();
  }
  float m = red_res;
  float e = expf(attl - m);
  {
    float v = e;
    for (int o = 32; o > 0; o >>= 1) v += __shfl_xor(v, o, 64);
    if (lane == 0) redp[wid] = v;
    __syncthreads();
    if (tid == 0)
      red_res = ((redp[0] + redp[1]) + (redp[2] + redp[3])) +
                ((redp[4] + redp[5]) + (redp[6] + redp[7]));
    __syncthreads();
  }
  float S = red_res;
  float al = e / S;
  alpha_ws[b * L_ + tid] = al;
  __builtin_nontemporal_store(al, out + ((size_t)b * L_ + t) * L_ + tid);
  float mval = mk[b * L_ + tid];
  {
    uint32_t k0, k1;
    step_key(t, k0, k1);
    float g = gumbel_for(k0, k1, (uint32_t)(b * L_ + tid));
    float pl = al * mval;
    float sv = logf(pl) + g;
    int si = tid;
    for (int o = 32; o > 0; o >>= 1) {
      float ov = __shfl_xor(sv, o, 64);
      int oi = __shfl_xor(si, o, 64);
      if (ov > sv || (ov == sv && oi < si)) { sv = ov; si = oi; }
    }
    if (lane == 0) { redp[wid] = sv; redpi[wid] = si; }
    __syncthreads();
    if (tid == 0) {
      float bv = redp[0];
      int bi = redpi[0];
#pragma unroll
      for (int w = 1; w < 8; ++w) {
        if (redp[w] > bv || (redp[w] == bv && redpi[w] < bi)) {
          bv = redp[w]; bi = redpi[w];
        }
      }
      red_resi = bi;
      mk[b * L_ + bi] = 0.0f;
      out[(size_t)B_ * L_ * L_ + (size_t)b * L_ + t] = (float)bi;
    }
    __syncthreads();
  }
  int idx = red_resi;
  if (tid < E_) x[b * E_ + tid] = embedded[((size_t)b * L_ + idx) * E_ + tid];
}

__global__ __launch_bounds__(256) void k_hs(
    const float* __restrict__ alpha_ws, const float* __restrict__ ctxT,
    float* __restrict__ hs_ws) {
  __shared__ float salpha[L_];
  int b = blockIdx.x >> 1;
  int kh = blockIdx.x & 1;
  int tid = threadIdx.x;
  int lane = tid & 63, wid = tid >> 6;
  salpha[tid] = alpha_ws[b * L_ + tid];
  salpha[tid + 256] = alpha_ws[b * L_ + tid + 256];
  __syncthreads();
  const float* ctb = ctxT + (size_t)b * H_ * L_;
  for (int mm = 0; mm < 32; ++mm) {
    int k = (kh * 4 + wid) * 32 + mm;
    const float* cr = ctb + (size_t)k * L_;
    float a = 0;
#pragma unroll
    for (int cch = 0; cch < 8; ++cch) {
      int l = lane + (cch << 6);
      a = fmaf(salpha[l], cr[l], a);
    }
    for (int o = 32; o > 0; o >>= 1) a += __shfl_xor(a, o, 64);
    if (lane == 0) hs_ws[b * H_ + k] = a;
  }
}

__global__ __launch_bounds__(256) void k_hnew(
    const float* __restrict__ hs_ws, const float* __restrict__ ht_ws,
    const float* __restrict__ Wout, const float* __restrict__ bout,
    float* __restrict__ h, float* __restrict__ out, int t) {
  __shared__ float shs[H_], sht[H_];
  int b = blockIdx.x, tid = threadIdx.x;
  shs[tid] = hs_ws[b * H_ + tid];
  sht[tid] = ht_ws[b * H_ + tid];
  __syncthreads();
  float a0 = 0, a1 = 0, a2 = 0, a3 = 0;
#pragma unroll 4
  for (int r = 0; r < H_; r += 4) {
    a0 = fmaf(shs[r],     Wout[(size_t)r * H_ + tid],       a0);
    a1 = fmaf(shs[r + 1], Wout[(size_t)(r + 1) * H_ + tid], a1);
    a2 = fmaf(shs[r + 2], Wout[(size_t)(r + 2) * H_ + tid], a2);
    a3 = fmaf(shs[r + 3], Wout[(size_t)(r + 3) * H_ + tid], a3);
  }
#pragma unroll 4
  for (int r = 0; r < H_; r += 4) {
    a0 = fmaf(sht[r],     Wout[(size_t)(H_ + r) * H_ + tid],     a0);
    a1 = fmaf(sht[r + 1], Wout[(size_t)(H_ + r + 1) * H_ + tid], a1);
    a2 = fmaf(sht[r + 2], Wout[(size_t)(H_ + r + 2) * H_ + tid], a2);
    a3 = fmaf(sht[r + 3], Wout[(size_t)(H_ + r + 3) * H_ + tid], a3);
  }
  float hn = tanhf((((a0 + a1) + (a2 + a3))) + bout[tid]);
  h[b * H_ + tid] = hn;
  if (t == L_ - 1) {
    float* outH = out + (size_t)B_ * L_ * L_ + (size_t)B_ * L_ + (size_t)b * H_;
    outH[tid] = hn;
  }
}

// ---------------------------------------------------------------------------
extern "C" void kernel_launch(void* const* d_in, const int* in_sizes, int n_in,
                              void* d_out, int out_size, void* d_ws, size_t ws_size,
                              hipStream_t stream) {
  const float* embedded = (const float*)d_in[0];
  const float* dec      = (const float*)d_in[1];
  const float* h0       = (const float*)d_in[2];
  const float* c0in     = (const float*)d_in[3];
  const float* context  = (const float*)d_in[4];
  const float* Wih      = (const float*)d_in[5];
  const float* bih      = (const float*)d_in[6];
  const float* Whh      = (const float*)d_in[7];
  const float* bhh      = (const float*)d_in[8];
  const float* Wout     = (const float*)d_in[9];
  const float* bout     = (const float*)d_in[10];
  const float* Winp     = (const float*)d_in[11];
  const float* binp     = (const float*)d_in[12];
  const float* Wctx     = (const float*)d_in[13];
  const float* bctx     = (const float*)d_in[14];
  const float* V        = (const float*)d_in[15];
  float* out = (float*)d_out;

  float* ws = (float*)d_ws;
  const size_t CTXF = (size_t)B_ * H_ * L_;   // 64 MB
  float* ctxT  = ws;
  float* gates = ctxT + CTXF;                 // 131072
  float* hbuf  = gates + (size_t)B_ * G4_;    // 32768 (fallback)
  float* cb0   = hbuf + (size_t)B_ * H_;      // 32768 (fallback)
  float* cb1   = cb0 + (size_t)B_ * H_;       // 32768 (fallback)
  float* htb   = cb1 + (size_t)B_ * H_;       // 32768 (fallback)
  float* xb    = htb + (size_t)B_ * H_;       // 16384 (fallback)
  float* attb  = xb + (size_t)B_ * E_;        // 65536
  float* alb   = attb + (size_t)B_ * L_;      // 65536 (fallback alpha; coop cnt)
  float* mkb   = alb + (size_t)B_ * L_;       // 65536 (fallback)
  float* hsb   = mkb + (size_t)B_ * L_;       // 32768
  unsigned* cnt = (unsigned*)alb;             // 4096 words used (coop only)
  size_t need_f = (size_t)(hsb + (size_t)B_ * H_ - ws);
  size_t need_bytes = need_f * sizeof(float);

  if (ws_size < need_bytes) return;

  ctx_precompute<<<dim3(B_ * 8), dim3(256), 0, stream>>>(context, Wctx, bctx, ctxT, cnt);

  void* args[] = {
    (void*)&embedded, (void*)&dec, (void*)&h0, (void*)&c0in,
    (void*)&Wih, (void*)&bih, (void*)&Whh, (void*)&bhh,
    (void*)&Wout, (void*)&bout, (void*)&Winp, (void*)&binp,
    (void*)&V, (void*)&ctxT, (void*)&gates, (void*)&attb,
    (void*)&hsb, (void*)&cnt, (void*)&out };
  hipError_t e = hipLaunchCooperativeKernel(
      (const void*)coop_scan, dim3(B_ * 2), dim3(512), args,
      TROWS * 256 * sizeof(float) /* 144 KB dynamic LDS ctx tile */, stream);

  if (e != hipSuccess) {
    // fallback: round-3 multi-kernel path (passed, 78 ms)
    k_init<<<dim3(B_), dim3(512), 0, stream>>>(h0, c0in, dec, hbuf, cb0, mkb, xb);
    for (int t = 0; t < L_; ++t) {
      float* crd = (t & 1) ? cb1 : cb0;
      float* cwr = (t & 1) ? cb0 : cb1;
      k_gates<<<dim3(B_ * 4), dim3(256), 0, stream>>>(Wih, bih, Whh, bhh, xb, hbuf, gates);
      k_lstm_att<<<dim3(B_ * 2), dim3(256), 0, stream>>>(
          gates, crd, cwr, htb, Winp, binp, V, ctxT, mkb, attb, out, t);
      k_sample<<<dim3(B_), dim3(512), 0, stream>>>(attb, mkb, alb, xb, embedded, out, t);
      k_hs<<<dim3(B_ * 2), dim3(256), 0, stream>>>(alb, ctxT, hsb);
      k_hnew<<<dim3(B_), dim3(256), 0, stream>>>(hsb, htb, Wout, bout, hbuf, out, t);
    }
  }
}